// Round 6
// baseline (218.963 us; speedup 1.0000x reference)
//
#include <hip/hip_runtime.h>
#include <hip/hip_bf16.h>

// B=16, S=2048, D=128 causal attention, pre-scale threshold:
//   A = Q@T^T; A = (A>0.3 ? A : 0); causal -2^32; /sqrt(128); softmax; @V
// fp32 in/out, bf16 MFMA internal. Fixed-max softmax (post-threshold logits
// in [0,~9] -> m=0 is safe, weights are absolute => no per-iter reductions).
//
// Round-6: round-5 structure (barrier-free k-loop, direct-global B-frags,
// ta single-buffered, vb prefetched) with the prep bug fixed: T cast is
// 16 elems/thread (4.19M / 262144 threads = 16, NOT 4 — round-5 left 3/4
// of Tb as 0xAA poison).

#define S_LEN 2048
#define D_DIM 128
#define BQ 64
#define BK 64
#define THRESH 0.3f
#define SCALE 0.08838834764831845f   // 1/sqrt(128)

typedef __bf16 bf16x8 __attribute__((ext_vector_type(8)));
typedef float f32x4 __attribute__((ext_vector_type(4)));

__device__ inline bf16x8 cvt8(const float* p) {
    f32x4 a = *(const f32x4*)p;
    f32x4 b = *(const f32x4*)(p + 4);
    bf16x8 r;
    #pragma unroll
    for (int j = 0; j < 4; ++j) { r[j] = (__bf16)a[j]; r[4 + j] = (__bf16)b[j]; }
    return r;
}

// ---- merged prep: T fp32->bf16 cast + V fp32 -> Vt[b][d][s] bf16 transpose ----
// 1024 blocks x 256 threads. Each thread casts 16 T elements (2x bf16x8).
template <bool DO_T>
__global__ void prep_kernel(const float* __restrict__ T, const float* __restrict__ V,
                            __bf16* __restrict__ Tb, __bf16* __restrict__ Vt) {
    int tid = threadIdx.x;
    if constexpr (DO_T) {
        size_t i = ((size_t)blockIdx.x * 256 + tid) * 16;   // 16 elems/thread
        *(bf16x8*)(Tb + i)     = cvt8(T + i);
        *(bf16x8*)(Tb + i + 8) = cvt8(T + i + 8);
    }
    __shared__ float tile[64][65];
    int bid = blockIdx.x;
    int b  = bid >> 6;
    int t2 = bid & 63;
    int s0 = (t2 >> 1) * 64;
    int d0 = (t2 & 1) * 64;
    #pragma unroll
    for (int it = 0; it < 2; ++it) {
        int row = it * 32 + (tid >> 3);
        int c   = (tid & 7) * 8;
        const float* p = V + ((size_t)b * S_LEN + s0 + row) * D_DIM + d0 + c;
        *(f32x4*)(&tile[row][c])     = *(const f32x4*)p;
        *(f32x4*)(&tile[row][c + 4]) = *(const f32x4*)(p + 4);
    }
    __syncthreads();
    #pragma unroll
    for (int it = 0; it < 2; ++it) {
        int dr = it * 32 + (tid >> 3);
        int c  = (tid & 7) * 8;
        bf16x8 w;
        #pragma unroll
        for (int j = 0; j < 8; ++j) w[j] = (__bf16)tile[c + j][dr];
        *(bf16x8*)(Vt + ((size_t)b * D_DIM + d0 + dr) * S_LEN + s0 + c) = w;
    }
}

// ---------------- Flash attention, barrier-free k-loop ----------------
// 256 threads = 4 independent waves; one block per (batch, 64-query tile);
// wave w owns q rows [q0+16w .. q0+16w+15]. MFMA 16x16x32 bf16.
// A-frag: A[m=lane&15][k=quad*8+j]; B-frag: B[n=lane&15][k=quad*8+j];
// C/D: col=lane&15, row=quad*4+r.
template <bool F32T>
__global__ __launch_bounds__(256, 2)
void fa_kernel(const float* __restrict__ Q, const void* __restrict__ Tsrc,
               const __bf16* __restrict__ Vt, float* __restrict__ O) {
    __shared__ __bf16 Pl[4][16 * 72];      // per-wave P transpose scratch

    int bid  = blockIdx.x;
    int b    = bid & 15;
    int half = bid >> 8;                   // pair (i, i+256): 33 iters total
    int idx  = (bid >> 4) & 15;
    int qt   = half == 0 ? (31 - idx) : idx;
    int q0   = qt * BQ;

    int tid  = threadIdx.x;
    int lane = tid & 63;
    int wave = tid >> 6;
    int col  = lane & 15;
    int quad = lane >> 4;

    // Q fragments (16 rows x D=128), converted to bf16 once.
    const float* qptr = Q + ((size_t)b * S_LEN + (q0 + wave * 16 + col)) * D_DIM + quad * 8;
    bf16x8 qf[4];
    #pragma unroll
    for (int kk = 0; kk < 4; ++kk) qf[kk] = cvt8(qptr + kk * 32);

    f32x4 oacc[8];
    #pragma unroll
    for (int dt = 0; dt < 8; ++dt) oacc[dt] = {0.f, 0.f, 0.f, 0.f};
    float lsum[4] = {0.f, 0.f, 0.f, 0.f};

    const __bf16* Tb  = (const __bf16*)Tsrc;
    const float*  Tf  = (const float*)Tsrc;
    const size_t tbof = (size_t)b * S_LEN * D_DIM + (size_t)col * D_DIM + quad * 8;
    const __bf16* Vb  = Vt + (size_t)b * D_DIM * S_LEN + (size_t)col * S_LEN + quad * 8;

    // V fragments, prefetched one iteration ahead (cross-iter live: 64 VGPR).
    bf16x8 vb[16];
    #pragma unroll
    for (int ks = 0; ks < 2; ++ks)
        #pragma unroll
        for (int dt = 0; dt < 8; ++dt)
            vb[ks * 8 + dt] = *(const bf16x8*)(Vb + (size_t)dt * 16 * S_LEN + ks * 32);

    for (int kt = 0; kt <= qt; ++kt) {
        int k0 = kt * BK;
        int kn = (kt < qt) ? k0 + BK : k0;     // clamped prefetch target

        // ---- T fragments for this tile (intra-iteration live range) ----
        bf16x8 ta[16];
        #pragma unroll
        for (int t = 0; t < 4; ++t)
            #pragma unroll
            for (int kk = 0; kk < 4; ++kk) {
                size_t off = tbof + (size_t)(k0 + t * 16) * D_DIM + kk * 32;
                if constexpr (F32T) ta[t * 4 + kk] = cvt8(Tf + off);
                else                ta[t * 4 + kk] = *(const bf16x8*)(Tb + off);
            }

        // ---- S = Q @ T^T (16 q-rows x 64 keys) ----
        f32x4 sacc[4];
        #pragma unroll
        for (int t = 0; t < 4; ++t) {
            sacc[t] = {0.f, 0.f, 0.f, 0.f};
            #pragma unroll
            for (int kk = 0; kk < 4; ++kk)
                sacc[t] = __builtin_amdgcn_mfma_f32_16x16x32_bf16(qf[kk], ta[t * 4 + kk], sacc[t], 0, 0, 0);
        }

        // ---- fixed-max softmax weights: masked?0 : (s>thr ? exp(s*sc) : 1) ----
        bool diag = (kt == qt);
        float p[4][4];
        #pragma unroll
        for (int t = 0; t < 4; ++t)
            #pragma unroll
            for (int r = 0; r < 4; ++r) {
                float s = sacc[t][r];
                float e = __expf(s * SCALE);
                float w = (s > THRESH) ? e : 1.0f;
                if (diag && (t * 16 + col > wave * 16 + quad * 4 + r)) w = 0.0f;
                p[t][r] = w;
            }
        #pragma unroll
        for (int r = 0; r < 4; ++r)
            lsum[r] += (p[0][r] + p[1][r]) + (p[2][r] + p[3][r]);

        // ---- P (C-layout) -> LDS -> A-layout (per-wave, no barrier) ----
        __bf16* pw = &Pl[wave][0];
        #pragma unroll
        for (int t = 0; t < 4; ++t)
            #pragma unroll
            for (int r = 0; r < 4; ++r)
                pw[(quad * 4 + r) * 72 + t * 16 + col] = (__bf16)p[t][r];

        asm volatile("s_waitcnt lgkmcnt(0)" ::: "memory");  // wave-local RAW on Pl

        #pragma unroll
        for (int ks = 0; ks < 2; ++ks) {
            bf16x8 af = *(const bf16x8*)(&pw[col * 72 + ks * 32 + quad * 8]);
            #pragma unroll
            for (int dt = 0; dt < 8; ++dt)
                oacc[dt] = __builtin_amdgcn_mfma_f32_16x16x32_bf16(af, vb[ks * 8 + dt], oacc[dt], 0, 0, 0);
        }

        // ---- prefetch next V fragments (full iteration of latency cover) ----
        #pragma unroll
        for (int ks = 0; ks < 2; ++ks)
            #pragma unroll
            for (int dt = 0; dt < 8; ++dt)
                vb[ks * 8 + dt] = *(const bf16x8*)(Vb + (size_t)dt * 16 * S_LEN + kn + ks * 32);
    }

    // ---- final l reduction across the 16 col-lanes, then store ----
    #pragma unroll
    for (int r = 0; r < 4; ++r) {
        float l = lsum[r];
        l += __shfl_xor(l, 1);
        l += __shfl_xor(l, 2);
        l += __shfl_xor(l, 4);
        l += __shfl_xor(l, 8);
        lsum[r] = 1.0f / l;                // diagonal tile always contributes >=1
    }
    float* optr = O + ((size_t)b * S_LEN + q0 + wave * 16) * D_DIM;
    #pragma unroll
    for (int dt = 0; dt < 8; ++dt)
        #pragma unroll
        for (int r = 0; r < 4; ++r)
            optr[(quad * 4 + r) * D_DIM + dt * 16 + col] = oacc[dt][r] * lsum[r];
}

extern "C" void kernel_launch(void* const* d_in, const int* in_sizes, int n_in,
                              void* d_out, int out_size, void* d_ws, size_t ws_size,
                              hipStream_t stream) {
    const float* Q = (const float*)d_in[0];
    const float* T = (const float*)d_in[1];
    const float* V = (const float*)d_in[2];
    float* O = (float*)d_out;

    const size_t HALF = (size_t)16 * 2048 * 128 * sizeof(__bf16);   // 8 MB

    if (ws_size >= 2 * HALF) {
        __bf16* Tb = (__bf16*)d_ws;
        __bf16* Vt = (__bf16*)((char*)d_ws + HALF);
        prep_kernel<true><<<1024, 256, 0, stream>>>(T, V, Tb, Vt);
        fa_kernel<false><<<512, 256, 0, stream>>>(Q, Tb, Vt, O);
    } else {
        __bf16* Vt = (__bf16*)d_ws;                                  // 8 MB
        prep_kernel<false><<<1024, 256, 0, stream>>>(T, V, nullptr, Vt);
        fa_kernel<true><<<512, 256, 0, stream>>>(Q, T, Vt, O);
    }
}

// Round 7
// 137.508 us; speedup vs baseline: 1.5924x; 1.5924x over previous
//
#include <hip/hip_runtime.h>
#include <hip/hip_bf16.h>

// B=16, S=2048, D=128 causal attention, pre-scale threshold:
//   A = Q@T^T; A = (A>0.3 ? A : 0); causal -2^32; /sqrt(128); softmax; @V
// fp32 in/out, bf16 MFMA internal. Fixed-max softmax (post-threshold logits
// in [0,~9] -> m=0 safe, weights absolute => no per-iter reductions).
//
// Round-7: barrier-free k-loop + FRAGMENT-PACKED global layouts.
// Round-6 lesson: direct-global frag loads with 256B/4KB lane strides are
// transaction-bound (16 scattered lines per instr, 4x redundant across waves)
// -> MfmaUtil 4.9%. Prep now packs T and V so every fragment load is
// base + lane*16 (one contiguous 1KB burst, L1-shared across waves).

#define S_LEN 2048
#define D_DIM 128
#define BQ 64
#define BK 64
#define THRESH 0.3f
#define SCALE 0.08838834764831845f   // 1/sqrt(128)

typedef __bf16 bf16x8 __attribute__((ext_vector_type(8)));
typedef float f32x4 __attribute__((ext_vector_type(4)));

__device__ inline bf16x8 cvt8(const float* p) {
    f32x4 a = *(const f32x4*)p;
    f32x4 b = *(const f32x4*)(p + 4);
    bf16x8 r;
    #pragma unroll
    for (int j = 0; j < 4; ++j) { r[j] = (__bf16)a[j]; r[4 + j] = (__bf16)b[j]; }
    return r;
}

// ---- prep: pack T and V into MFMA-fragment order (bf16) ----
// Tp[(((b*128+st)*4+kk)*64 + quad*16+col)*8 + j] = T[b][st*16+col][kk*32+quad*8+j]
// Vp[(((b*8+dt)*64+kb)*64 + quad*16+col)*8 + j]  = V[b][kb*32+quad*8+j][dt*16+col]
// DO_T=true: 2048 blocks (T-pack all, V-pack on bid<1024). DO_T=false: 1024.
template <bool DO_T>
__global__ void prep_kernel(const float* __restrict__ T, const float* __restrict__ V,
                            __bf16* __restrict__ Tp, __bf16* __restrict__ Vp) {
    int tid = threadIdx.x;
    int bid = blockIdx.x;
    if constexpr (DO_T) {
        size_t g = (size_t)bid * 256 + tid;
        size_t i = g * 8;                       // 8 contiguous fp32 per thread
        int row = (int)(i >> 7);                // b*2048+s
        int c8  = (int)(i >> 3) & 15;
        int b = row >> 11, s = row & 2047;
        int st = s >> 4, col = s & 15;
        int kk = c8 >> 2, quad = c8 & 3;
        size_t o = ((((size_t)b * 128 + st) * 4 + kk) * 64 + quad * 16 + col) * 8;
        *(bf16x8*)(Tp + o) = cvt8(T + i);
    }
    if (bid < 1024) {
        __shared__ float tile[64][65];
        int b  = bid >> 6;
        int t2 = bid & 63;
        int s0 = (t2 >> 1) * 64;
        int d0 = (t2 & 1) * 64;
        #pragma unroll
        for (int it = 0; it < 2; ++it) {
            int row = it * 32 + (tid >> 3);
            int c   = (tid & 7) * 8;
            const float* p = V + ((size_t)b * S_LEN + s0 + row) * D_DIM + d0 + c;
            *(f32x4*)(&tile[row][c])     = *(const f32x4*)p;
            *(f32x4*)(&tile[row][c + 4]) = *(const f32x4*)(p + 4);
        }
        __syncthreads();
        #pragma unroll
        for (int it = 0; it < 2; ++it) {
            int dr = it * 32 + (tid >> 3);      // d-local
            int c  = (tid & 7) * 8;             // s-local, multiple of 8
            int d  = d0 + dr;
            int sb = s0 + c;
            int dt = d >> 4, coln = d & 15;
            int kb = sb >> 5, quad = (sb >> 3) & 3;
            bf16x8 w;
            #pragma unroll
            for (int j = 0; j < 8; ++j) w[j] = (__bf16)tile[c + j][dr];
            size_t o = ((((size_t)b * 8 + dt) * 64 + kb) * 64 + quad * 16 + coln) * 8;
            *(bf16x8*)(Vp + o) = w;
        }
    }
}

// ---------------- Flash attention, barrier-free k-loop ----------------
// 256 threads = 4 independent waves; one block per (batch, 64-query tile);
// wave w owns q rows [q0+16w .. q0+16w+15]. MFMA 16x16x32 bf16.
// A-frag: A[m=lane&15][k=quad*8+j]; B-frag: B[n=lane&15][k=quad*8+j];
// C/D: col=lane&15, row=quad*4+r.
template <bool F32T>
__global__ __launch_bounds__(256, 2)
void fa_kernel(const float* __restrict__ Q, const void* __restrict__ Tsrc,
               const __bf16* __restrict__ Vp, float* __restrict__ O) {
    __shared__ __bf16 Pl[4][16 * 72];      // per-wave P transpose scratch

    int bid  = blockIdx.x;
    int b    = bid & 15;
    int half = bid >> 8;                   // pair (i, i+256): 33 iters total
    int idx  = (bid >> 4) & 15;
    int qt   = half == 0 ? (31 - idx) : idx;
    int q0   = qt * BQ;

    int tid  = threadIdx.x;
    int lane = tid & 63;
    int wave = tid >> 6;
    int col  = lane & 15;
    int quad = lane >> 4;

    // Q fragments (16 rows x D=128), converted to bf16 once.
    const float* qptr = Q + ((size_t)b * S_LEN + (q0 + wave * 16 + col)) * D_DIM + quad * 8;
    bf16x8 qf[4];
    #pragma unroll
    for (int kk = 0; kk < 4; ++kk) qf[kk] = cvt8(qptr + kk * 32);

    f32x4 oacc[8];
    #pragma unroll
    for (int dt = 0; dt < 8; ++dt) oacc[dt] = {0.f, 0.f, 0.f, 0.f};
    float lsum[4] = {0.f, 0.f, 0.f, 0.f};

    // Packed bases (256 KB per batch each).
    const __bf16* Tbase = (const __bf16*)Tsrc + (size_t)b * 262144 + (size_t)lane * 8;
    const __bf16* Vbase = Vp + (size_t)b * 262144 + (size_t)lane * 8;
    // Fallback: scattered fp32 T reads with inline cvt.
    const float* Tf   = (const float*)Tsrc;
    const size_t tbof = (size_t)b * S_LEN * D_DIM + (size_t)col * D_DIM + quad * 8;

    bf16x8 ta[16];   // T fragments [t*4+kk] — 16 KB contiguous per k-tile
    bf16x8 vb[16];   // V fragments [ks*8+dt]

    #pragma unroll
    for (int i = 0; i < 16; ++i) {
        if constexpr (F32T) {
            int t = i >> 2, kk = i & 3;
            ta[i] = cvt8(Tf + tbof + (size_t)(t * 16) * D_DIM + kk * 32);
        } else {
            ta[i] = *(const bf16x8*)(Tbase + (size_t)i * 512);
        }
    }
    #pragma unroll
    for (int ks = 0; ks < 2; ++ks)
        #pragma unroll
        for (int dt = 0; dt < 8; ++dt)
            vb[ks * 8 + dt] = *(const bf16x8*)(Vbase + (size_t)(dt * 64 + ks) * 512);

    for (int kt = 0; kt <= qt; ++kt) {
        bool adv = kt < qt;
        int ktn  = adv ? kt + 1 : kt;

        // ---- S = Q @ T^T (16 q-rows x 64 keys) ----
        f32x4 sacc[4];
        #pragma unroll
        for (int t = 0; t < 4; ++t) {
            sacc[t] = {0.f, 0.f, 0.f, 0.f};
            #pragma unroll
            for (int kk = 0; kk < 4; ++kk)
                sacc[t] = __builtin_amdgcn_mfma_f32_16x16x32_bf16(qf[kk], ta[t * 4 + kk], sacc[t], 0, 0, 0);
        }

        // ---- early prefetch of next T fragments (ta now dead) ----
        if (adv) {
            #pragma unroll
            for (int i = 0; i < 16; ++i) {
                if constexpr (F32T) {
                    int t = i >> 2, kk = i & 3;
                    ta[i] = cvt8(Tf + tbof + (size_t)(ktn * 64 + t * 16) * D_DIM + kk * 32);
                } else {
                    ta[i] = *(const bf16x8*)(Tbase + (size_t)(ktn * 16 + i) * 512);
                }
            }
        }

        // ---- fixed-max softmax weights: masked?0 : (s>thr ? exp(s*sc) : 1) ----
        bool diag = (kt == qt);
        float p[4][4];
        #pragma unroll
        for (int t = 0; t < 4; ++t)
            #pragma unroll
            for (int r = 0; r < 4; ++r) {
                float s = sacc[t][r];
                float e = __expf(s * SCALE);
                float w = (s > THRESH) ? e : 1.0f;
                if (diag && (t * 16 + col > wave * 16 + quad * 4 + r)) w = 0.0f;
                p[t][r] = w;
            }
        #pragma unroll
        for (int r = 0; r < 4; ++r)
            lsum[r] += (p[0][r] + p[1][r]) + (p[2][r] + p[3][r]);

        // ---- P (C-layout) -> LDS -> A-layout (per-wave, no barrier) ----
        __bf16* pw = &Pl[wave][0];
        #pragma unroll
        for (int t = 0; t < 4; ++t)
            #pragma unroll
            for (int r = 0; r < 4; ++r)
                pw[(quad * 4 + r) * 72 + t * 16 + col] = (__bf16)p[t][r];

        asm volatile("s_waitcnt lgkmcnt(0)" ::: "memory");  // wave-local RAW on Pl

        #pragma unroll
        for (int ks = 0; ks < 2; ++ks) {
            bf16x8 af = *(const bf16x8*)(&pw[col * 72 + ks * 32 + quad * 8]);
            #pragma unroll
            for (int dt = 0; dt < 8; ++dt)
                oacc[dt] = __builtin_amdgcn_mfma_f32_16x16x32_bf16(af, vb[ks * 8 + dt], oacc[dt], 0, 0, 0);
        }

        // ---- prefetch next V fragments (vb now dead) ----
        if (adv) {
            #pragma unroll
            for (int ks = 0; ks < 2; ++ks)
                #pragma unroll
                for (int dt = 0; dt < 8; ++dt)
                    vb[ks * 8 + dt] = *(const bf16x8*)(Vbase + (size_t)(dt * 64 + ktn * 2 + ks) * 512);
        }
    }

    // ---- final l reduction across the 16 col-lanes, then store ----
    #pragma unroll
    for (int r = 0; r < 4; ++r) {
        float l = lsum[r];
        l += __shfl_xor(l, 1);
        l += __shfl_xor(l, 2);
        l += __shfl_xor(l, 4);
        l += __shfl_xor(l, 8);
        lsum[r] = 1.0f / l;                // diagonal tile always contributes >=1
    }
    float* optr = O + ((size_t)b * S_LEN + q0 + wave * 16) * D_DIM;
    #pragma unroll
    for (int dt = 0; dt < 8; ++dt)
        #pragma unroll
        for (int r = 0; r < 4; ++r)
            optr[(quad * 4 + r) * D_DIM + dt * 16 + col] = oacc[dt][r] * lsum[r];
}

extern "C" void kernel_launch(void* const* d_in, const int* in_sizes, int n_in,
                              void* d_out, int out_size, void* d_ws, size_t ws_size,
                              hipStream_t stream) {
    const float* Q = (const float*)d_in[0];
    const float* T = (const float*)d_in[1];
    const float* V = (const float*)d_in[2];
    float* O = (float*)d_out;

    const size_t HALF = (size_t)16 * 2048 * 128 * sizeof(__bf16);   // 8 MB

    if (ws_size >= 2 * HALF) {
        __bf16* Vp = (__bf16*)d_ws;
        __bf16* Tp = (__bf16*)((char*)d_ws + HALF);
        prep_kernel<true><<<2048, 256, 0, stream>>>(T, V, Tp, Vp);
        fa_kernel<false><<<512, 256, 0, stream>>>(Q, Tp, Vp, O);
    } else {
        __bf16* Vp = (__bf16*)d_ws;                                  // 8 MB
        prep_kernel<false><<<1024, 256, 0, stream>>>(T, V, nullptr, Vp);
        fa_kernel<true><<<512, 256, 0, stream>>>(Q, T, Vp, O);
    }
}